// Round 1
// baseline (5328.261 us; speedup 1.0000x reference)
//
#include <hip/hip_runtime.h>
#include <hip/hip_bf16.h>

#define NN 50000
#define EE 800000
#define HH 256
#define GG 128
#define LL 5

// ---------------- atom encoder: x[n,h] = sum_f atom_emb[f, feat[n,f], h] ----------------
__global__ __launch_bounds__(256) void k_encode(const int* __restrict__ xf,
                                                const float* __restrict__ atom_emb,
                                                float* __restrict__ x) {
    int n = blockIdx.x, h = threadIdx.x;
    float s = 0.f;
#pragma unroll
    for (int f = 0; f < 9; ++f) {
        int v = xf[n * 9 + f];
        s += atom_emb[((size_t)f * 64 + v) * HH + h];
    }
    x[(size_t)n * HH + h] = s;
}

// ---------------- copy (init agg = x) ----------------
__global__ void k_copy4(const float4* __restrict__ src, float4* __restrict__ dst, size_t n4) {
    size_t i = (size_t)blockIdx.x * blockDim.x + threadIdx.x;
    size_t stride = (size_t)gridDim.x * blockDim.x;
    for (; i < n4; i += stride) dst[i] = src[i];
}

// ---------------- message + scatter: agg[dst] += relu(x[src] + e) ----------------
__global__ __launch_bounds__(256) void k_message(const float* __restrict__ x,
                                                 const int* __restrict__ ei,
                                                 const int* __restrict__ attr,
                                                 const float* __restrict__ bond_emb,
                                                 float* __restrict__ agg) {
    int e = blockIdx.x;
    int h = threadIdx.x;
    int s = ei[e];
    int d = ei[EE + e];
    int a0 = attr[e * 3 + 0];
    int a1 = attr[e * 3 + 1];
    int a2 = attr[e * 3 + 2];
    float eh = bond_emb[((size_t)0 * 8 + a0) * HH + h]
             + bond_emb[((size_t)1 * 8 + a1) * HH + h]
             + bond_emb[((size_t)2 * 8 + a2) * HH + h];
    float m = fmaxf(x[(size_t)s * HH + h] + eh, 0.f);
    atomicAdd(&agg[(size_t)d * HH + h], m);
}

// ---------------- GEMM: Out[M,256] = A[M,256] @ W[256,256] + bias, optional relu ----------------
// 64x64 tile, 16x16 threads, 4x4 per thread, K staged in chunks of 16.
__global__ __launch_bounds__(256) void k_gemm(const float* __restrict__ A,
                                              const float* __restrict__ W,
                                              const float* __restrict__ bias,
                                              float* __restrict__ Out,
                                              int M, int do_relu) {
    __shared__ float As[16][68];  // As[k][m]
    __shared__ float Bs[16][68];  // Bs[k][n]
    const int t = threadIdx.x;
    const int tx = t & 15;   // n quadrant
    const int ty = t >> 4;   // m quadrant
    const int m0 = blockIdx.x * 64, n0 = blockIdx.y * 64;

    const int lm = t >> 2;          // 0..63 row for A staging
    const int lk = (t & 3) * 4;     // 0,4,8,12
    const int bk = t >> 4;          // 0..15 k for B staging
    const int bn = (t & 15) * 4;    // 0..60

    float acc[4][4] = {{0.f}};

    for (int kb = 0; kb < 256; kb += 16) {
        float4 av;
        if (m0 + lm < M)
            av = *reinterpret_cast<const float4*>(&A[(size_t)(m0 + lm) * HH + kb + lk]);
        else
            av = make_float4(0.f, 0.f, 0.f, 0.f);
        As[lk + 0][lm] = av.x;
        As[lk + 1][lm] = av.y;
        As[lk + 2][lm] = av.z;
        As[lk + 3][lm] = av.w;
        float4 bv = *reinterpret_cast<const float4*>(&W[(size_t)(kb + bk) * HH + n0 + bn]);
        *reinterpret_cast<float4*>(&Bs[bk][bn]) = bv;
        __syncthreads();
#pragma unroll
        for (int kk = 0; kk < 16; ++kk) {
            float4 a4 = *reinterpret_cast<const float4*>(&As[kk][ty * 4]);
            float4 b4 = *reinterpret_cast<const float4*>(&Bs[kk][tx * 4]);
            float ar[4] = {a4.x, a4.y, a4.z, a4.w};
            float br[4] = {b4.x, b4.y, b4.z, b4.w};
#pragma unroll
            for (int i = 0; i < 4; ++i)
#pragma unroll
                for (int j = 0; j < 4; ++j)
                    acc[i][j] = fmaf(ar[i], br[j], acc[i][j]);
        }
        __syncthreads();
    }

#pragma unroll
    for (int i = 0; i < 4; ++i) {
        int m = m0 + ty * 4 + i;
        if (m < M) {
#pragma unroll
            for (int j = 0; j < 4; ++j) {
                int n = n0 + tx * 4 + j;
                float v = acc[i][j] + bias[n];
                if (do_relu) v = fmaxf(v, 0.f);
                Out[(size_t)m * HH + n] = v;
            }
        }
    }
}

// ---------------- BN stats: per-column sum / sumsq ----------------
__global__ __launch_bounds__(256) void k_bnstats(const float* __restrict__ Y, int M,
                                                 float* __restrict__ ssum,
                                                 float* __restrict__ ssq) {
    int h = threadIdx.x;
    float s = 0.f, q = 0.f;
    for (int r = blockIdx.x; r < M; r += gridDim.x) {
        float v = Y[(size_t)r * HH + h];
        s += v;
        q = fmaf(v, v, q);
    }
    atomicAdd(&ssum[h], s);
    atomicAdd(&ssq[h], q);
}

__global__ void k_bncoeff(const float* __restrict__ ssum, const float* __restrict__ ssq,
                          const float* __restrict__ g, const float* __restrict__ be,
                          float* __restrict__ ca, float* __restrict__ cb, float invN) {
    int h = threadIdx.x;
    float mu = ssum[h] * invN;
    float var = ssq[h] * invN - mu * mu;
    float a = g[h] * rsqrtf(var + 1e-5f);
    ca[h] = a;
    cb[h] = fmaf(-mu, a, be[h]);
}

// ---------------- BN apply + relu (elementwise) ----------------
__global__ void k_bnapply(const float* __restrict__ Y, float* __restrict__ Outp,
                          const float* __restrict__ ca, const float* __restrict__ cb,
                          size_t total) {
    size_t i = (size_t)blockIdx.x * blockDim.x + threadIdx.x;
    size_t stride = (size_t)gridDim.x * blockDim.x;
    for (; i < total; i += stride) {
        int h = (int)(i & (HH - 1));
        Outp[i] = fmaxf(fmaf(Y[i], ca[h], cb[h]), 0.f);
    }
}

// ---------------- pool: out[batch[n]] += y[n] ----------------
__global__ __launch_bounds__(256) void k_pool(const float* __restrict__ y,
                                              const int* __restrict__ batch,
                                              float* __restrict__ out) {
    int n = blockIdx.x, h = threadIdx.x;
    int g = batch[n];
    atomicAdd(&out[(size_t)g * HH + h], y[(size_t)n * HH + h]);
}

extern "C" void kernel_launch(void* const* d_in, const int* in_sizes, int n_in,
                              void* d_out, int out_size, void* d_ws, size_t ws_size,
                              hipStream_t stream) {
    const int* x_feat = (const int*)d_in[0];
    const int* ei = (const int*)d_in[1];
    const int* attr = (const int*)d_in[2];
    const int* batch = (const int*)d_in[3];
    const float* atom_emb = (const float*)d_in[4];
    const float* bond_emb = (const float*)d_in[5];
    const float* W1 = (const float*)d_in[6];
    const float* b1 = (const float*)d_in[7];
    const float* g1 = (const float*)d_in[8];
    const float* be1 = (const float*)d_in[9];
    const float* W2 = (const float*)d_in[10];
    const float* b2 = (const float*)d_in[11];
    const float* g2 = (const float*)d_in[12];
    const float* be2 = (const float*)d_in[13];
    const float* outW1 = (const float*)d_in[14];
    const float* outb1 = (const float*)d_in[15];
    const float* outg = (const float*)d_in[16];
    const float* outbe = (const float*)d_in[17];
    const float* outW2 = (const float*)d_in[18];
    const float* outb2 = (const float*)d_in[19];
    float* out = (float*)d_out;

    char* ws = (char*)d_ws;
    const size_t NH_BYTES = (size_t)NN * HH * sizeof(float);
    float* bufX = (float*)ws;
    float* bufB = (float*)(ws + NH_BYTES);
    float* bufC = (float*)(ws + 2 * NH_BYTES);
    float* ssum = (float*)(ws + 3 * NH_BYTES);
    float* ssq = ssum + HH;
    float* ca = ssum + 2 * HH;
    float* cb = ssum + 3 * HH;

    const float invN = 1.0f / (float)NN;
    const size_t totalNH = (size_t)NN * HH;
    const dim3 ggrid(782, 4);

    k_encode<<<NN, 256, 0, stream>>>(x_feat, atom_emb, bufX);

    float* x = bufX;
    float* tmp = bufB;
    float* y = bufC;

    for (int l = 0; l < LL; ++l) {
        // agg = x, then agg += sum_j relu(x[src]+e)  -> h = x + agg
        k_copy4<<<2048, 256, 0, stream>>>((const float4*)x, (float4*)tmp, totalNH / 4);
        k_message<<<EE, 256, 0, stream>>>(x, ei, attr, bond_emb, tmp);
        // y = h @ W1 + b1 ; bn ; relu
        k_gemm<<<ggrid, 256, 0, stream>>>(tmp, W1 + (size_t)l * HH * HH, b1 + l * HH, y, NN, 0);
        hipMemsetAsync(ssum, 0, 2 * HH * sizeof(float), stream);
        k_bnstats<<<256, 256, 0, stream>>>(y, NN, ssum, ssq);
        k_bncoeff<<<1, 256, 0, stream>>>(ssum, ssq, g1 + l * HH, be1 + l * HH, ca, cb, invN);
        k_bnapply<<<2048, 256, 0, stream>>>(y, y, ca, cb, totalNH);
        // tmp = relu(y @ W2 + b2)
        k_gemm<<<ggrid, 256, 0, stream>>>(y, W2 + (size_t)l * HH * HH, b2 + l * HH, tmp, NN, 1);
        // x = relu(bn(tmp))
        hipMemsetAsync(ssum, 0, 2 * HH * sizeof(float), stream);
        k_bnstats<<<256, 256, 0, stream>>>(tmp, NN, ssum, ssq);
        k_bncoeff<<<1, 256, 0, stream>>>(ssum, ssq, g2 + l * HH, be2 + l * HH, ca, cb, invN);
        k_bnapply<<<2048, 256, 0, stream>>>(tmp, tmp, ca, cb, totalNH);
        // rotate: new x = tmp, spare = old x
        float* oldx = x;
        x = tmp;
        tmp = oldx;
    }

    // head: y = relu(bn(x @ outW1 + outb1)); tmp = y @ outW2 + outb2; pool
    k_gemm<<<ggrid, 256, 0, stream>>>(x, outW1, outb1, y, NN, 0);
    hipMemsetAsync(ssum, 0, 2 * HH * sizeof(float), stream);
    k_bnstats<<<256, 256, 0, stream>>>(y, NN, ssum, ssq);
    k_bncoeff<<<1, 256, 0, stream>>>(ssum, ssq, outg, outbe, ca, cb, invN);
    k_bnapply<<<2048, 256, 0, stream>>>(y, y, ca, cb, totalNH);
    k_gemm<<<ggrid, 256, 0, stream>>>(y, outW2, outb2, tmp, NN, 0);

    hipMemsetAsync(d_out, 0, (size_t)GG * HH * sizeof(float), stream);
    k_pool<<<NN, 256, 0, stream>>>(tmp, batch, out);
}

// Round 2
// 2672.191 us; speedup vs baseline: 1.9940x; 1.9940x over previous
//
#include <hip/hip_runtime.h>
#include <hip/hip_bf16.h>

#define NN 50000
#define EE 800000
#define HH 256
#define GG 128
#define LL 5
#define NCHUNK 196  // ceil((NN+1)/256)

// ---------------- atom encoder: x[n,h] = sum_f atom_emb[f, feat[n,f], h] ----------------
__global__ __launch_bounds__(256) void k_encode(const int* __restrict__ xf,
                                                const float* __restrict__ atom_emb,
                                                float* __restrict__ x) {
    int n = blockIdx.x, h = threadIdx.x;
    float s = 0.f;
#pragma unroll
    for (int f = 0; f < 9; ++f) {
        int v = xf[n * 9 + f];
        s += atom_emb[((size_t)f * 64 + v) * HH + h];
    }
    x[(size_t)n * HH + h] = s;
}

// ---------------- CSR build ----------------
__global__ __launch_bounds__(256) void k_hist(const int* __restrict__ ei, int* __restrict__ deg) {
    int e = blockIdx.x * 256 + threadIdx.x;
    if (e < EE) atomicAdd(&deg[ei[EE + e]], 1);
}

// chunk-local exclusive scan; chunk totals to bsum
__global__ __launch_bounds__(256) void k_scan_a(const int* __restrict__ deg, int* __restrict__ ro,
                                                int* __restrict__ bsum) {
    __shared__ int sm[256];
    int b = blockIdx.x, t = threadIdx.x;
    int idx = b * 256 + t;
    int v = (idx < NN) ? deg[idx] : 0;
    sm[t] = v;
    __syncthreads();
    for (int off = 1; off < 256; off <<= 1) {
        int add = (t >= off) ? sm[t - off] : 0;
        __syncthreads();
        sm[t] += add;
        __syncthreads();
    }
    if (idx <= NN) ro[idx] = sm[t] - v;  // exclusive, chunk-local
    if (t == 255) bsum[b] = sm[255];
}

__global__ __launch_bounds__(256) void k_scan_b(int* __restrict__ bsum) {
    __shared__ int sm[256];
    int t = threadIdx.x;
    int v = (t < NCHUNK) ? bsum[t] : 0;
    sm[t] = v;
    __syncthreads();
    for (int off = 1; off < 256; off <<= 1) {
        int add = (t >= off) ? sm[t - off] : 0;
        __syncthreads();
        sm[t] += add;
        __syncthreads();
    }
    if (t < NCHUNK) bsum[t] = sm[t] - v;  // exclusive
}

__global__ __launch_bounds__(256) void k_scan_c(int* __restrict__ ro, const int* __restrict__ bsum,
                                                int* __restrict__ cursor) {
    int b = blockIdx.x, t = threadIdx.x;
    int idx = b * 256 + t;
    if (idx <= NN) {
        int val = ro[idx] + bsum[b];
        ro[idx] = val;
        if (idx < NN) cursor[idx] = val;
    }
}

__global__ __launch_bounds__(256) void k_scatter(const int* __restrict__ ei,
                                                 const int* __restrict__ attr,
                                                 int* __restrict__ cursor,
                                                 int4* __restrict__ ebuf) {
    int e = blockIdx.x * 256 + threadIdx.x;
    if (e < EE) {
        int d = ei[EE + e];
        int pos = atomicAdd(&cursor[d], 1);
        ebuf[pos] = make_int4(ei[e], attr[e * 3], attr[e * 3 + 1], attr[e * 3 + 2]);
    }
}

// ---------------- fused aggregate ----------------
// aggout[n] = T(t[n]) + sum_{e in in(n)} relu(T(t[src(e)]) + bond(e))
// T(v) = ca ? max(v*ca+cb, 0) : v        (folds prev layer's BN+relu)
// one 64-lane wave per node, float4 per lane.
__global__ __launch_bounds__(256) void k_aggregate(const float* __restrict__ t,
                                                   const int* __restrict__ ro,
                                                   const int4* __restrict__ ebuf,
                                                   const float* __restrict__ bond_emb,
                                                   const float* __restrict__ ca,
                                                   const float* __restrict__ cb,
                                                   float* __restrict__ aggout) {
    int grp = threadIdx.x >> 6;
    int lane = threadIdx.x & 63;
    int n = blockIdx.x * 4 + grp;
    if (n >= NN) return;
    int h4 = lane * 4;
    float4 cav = make_float4(1.f, 1.f, 1.f, 1.f);
    float4 cbv = make_float4(0.f, 0.f, 0.f, 0.f);
    bool has_t = (ca != nullptr);
    if (has_t) {
        cav = *reinterpret_cast<const float4*>(&ca[h4]);
        cbv = *reinterpret_cast<const float4*>(&cb[h4]);
    }
    float4 tv = *reinterpret_cast<const float4*>(&t[(size_t)n * HH + h4]);
    float4 acc;
    if (has_t) {
        acc.x = fmaxf(fmaf(tv.x, cav.x, cbv.x), 0.f);
        acc.y = fmaxf(fmaf(tv.y, cav.y, cbv.y), 0.f);
        acc.z = fmaxf(fmaf(tv.z, cav.z, cbv.z), 0.f);
        acc.w = fmaxf(fmaf(tv.w, cav.w, cbv.w), 0.f);
    } else {
        acc = tv;
    }
    int e0 = ro[n], e1 = ro[n + 1];
    for (int j = e0; j < e1; ++j) {
        int4 er = ebuf[j];
        const float4 b0 = *reinterpret_cast<const float4*>(&bond_emb[(size_t)(0 * 8 + er.y) * HH + h4]);
        const float4 b1 = *reinterpret_cast<const float4*>(&bond_emb[(size_t)(1 * 8 + er.z) * HH + h4]);
        const float4 b2 = *reinterpret_cast<const float4*>(&bond_emb[(size_t)(2 * 8 + er.w) * HH + h4]);
        float4 xs = *reinterpret_cast<const float4*>(&t[(size_t)er.x * HH + h4]);
        float vx, vy, vz, vw;
        if (has_t) {
            vx = fmaxf(fmaf(xs.x, cav.x, cbv.x), 0.f);
            vy = fmaxf(fmaf(xs.y, cav.y, cbv.y), 0.f);
            vz = fmaxf(fmaf(xs.z, cav.z, cbv.z), 0.f);
            vw = fmaxf(fmaf(xs.w, cav.w, cbv.w), 0.f);
        } else {
            vx = xs.x; vy = xs.y; vz = xs.z; vw = xs.w;
        }
        acc.x += fmaxf(vx + b0.x + b1.x + b2.x, 0.f);
        acc.y += fmaxf(vy + b0.y + b1.y + b2.y, 0.f);
        acc.z += fmaxf(vz + b0.z + b1.z + b2.z, 0.f);
        acc.w += fmaxf(vw + b0.w + b1.w + b2.w, 0.f);
    }
    *reinterpret_cast<float4*>(&aggout[(size_t)n * HH + h4]) = acc;
}

// ---------------- GEMM: Out[M,256] = T(A)[M,256] @ W[256,256] + bias ----------------
// T(a)[m][k] = tca ? max(a*tca[k]+tcb[k], 0) : a     (folds BN+relu on input)
// optional relu on output; optional per-column sum/sumsq stats (atomics).
__global__ __launch_bounds__(256) void k_gemm(const float* __restrict__ A,
                                              const float* __restrict__ W,
                                              const float* __restrict__ bias,
                                              float* __restrict__ Out,
                                              int M, int do_relu,
                                              const float* __restrict__ tca,
                                              const float* __restrict__ tcb,
                                              float* __restrict__ ssum,
                                              float* __restrict__ ssq) {
    __shared__ float As[16][68];  // As[k][m]
    __shared__ float Bs[16][68];  // Bs[k][n]
    const int t = threadIdx.x;
    const int tx = t & 15;
    const int ty = t >> 4;
    const int m0 = blockIdx.x * 64, n0 = blockIdx.y * 64;

    const int lm = t >> 2;
    const int lk = (t & 3) * 4;
    const int bk = t >> 4;
    const int bn = (t & 15) * 4;

    float acc[4][4] = {{0.f}};

    for (int kb = 0; kb < 256; kb += 16) {
        float4 av;
        if (m0 + lm < M)
            av = *reinterpret_cast<const float4*>(&A[(size_t)(m0 + lm) * HH + kb + lk]);
        else
            av = make_float4(0.f, 0.f, 0.f, 0.f);
        if (tca) {
            float4 cav = *reinterpret_cast<const float4*>(&tca[kb + lk]);
            float4 cbv = *reinterpret_cast<const float4*>(&tcb[kb + lk]);
            av.x = fmaxf(fmaf(av.x, cav.x, cbv.x), 0.f);
            av.y = fmaxf(fmaf(av.y, cav.y, cbv.y), 0.f);
            av.z = fmaxf(fmaf(av.z, cav.z, cbv.z), 0.f);
            av.w = fmaxf(fmaf(av.w, cav.w, cbv.w), 0.f);
        }
        As[lk + 0][lm] = av.x;
        As[lk + 1][lm] = av.y;
        As[lk + 2][lm] = av.z;
        As[lk + 3][lm] = av.w;
        float4 bv = *reinterpret_cast<const float4*>(&W[(size_t)(kb + bk) * HH + n0 + bn]);
        *reinterpret_cast<float4*>(&Bs[bk][bn]) = bv;
        __syncthreads();
#pragma unroll
        for (int kk = 0; kk < 16; ++kk) {
            float4 a4 = *reinterpret_cast<const float4*>(&As[kk][ty * 4]);
            float4 b4 = *reinterpret_cast<const float4*>(&Bs[kk][tx * 4]);
            float ar[4] = {a4.x, a4.y, a4.z, a4.w};
            float br[4] = {b4.x, b4.y, b4.z, b4.w};
#pragma unroll
            for (int i = 0; i < 4; ++i)
#pragma unroll
                for (int j = 0; j < 4; ++j)
                    acc[i][j] = fmaf(ar[i], br[j], acc[i][j]);
        }
        __syncthreads();
    }

    float vout[4][4];
#pragma unroll
    for (int i = 0; i < 4; ++i) {
        int m = m0 + ty * 4 + i;
        bool valid = m < M;
#pragma unroll
        for (int j = 0; j < 4; ++j) {
            int n = n0 + tx * 4 + j;
            float v = acc[i][j] + bias[n];
            if (do_relu) v = fmaxf(v, 0.f);
            if (valid) Out[(size_t)m * HH + n] = v;
            vout[i][j] = valid ? v : 0.f;
        }
    }

    if (ssum) {
        float* cs = &As[0][0];  // 64 floats
        float* cq = &Bs[0][0];
        if (t < 64) { cs[t] = 0.f; cq[t] = 0.f; }
        __syncthreads();
#pragma unroll
        for (int j = 0; j < 4; ++j) {
            float ps = 0.f, pq = 0.f;
#pragma unroll
            for (int i = 0; i < 4; ++i) {
                float v = vout[i][j];
                ps += v;
                pq = fmaf(v, v, pq);
            }
            atomicAdd(&cs[tx * 4 + j], ps);
            atomicAdd(&cq[tx * 4 + j], pq);
        }
        __syncthreads();
        if (t < 64) {
            atomicAdd(&ssum[n0 + t], cs[t]);
            atomicAdd(&ssq[n0 + t], cq[t]);
        }
    }
}

__global__ void k_bncoeff(const float* __restrict__ ssum, const float* __restrict__ ssq,
                          const float* __restrict__ g, const float* __restrict__ be,
                          float* __restrict__ ca, float* __restrict__ cb, float invN) {
    int h = threadIdx.x;
    float mu = ssum[h] * invN;
    float var = ssq[h] * invN - mu * mu;
    float a = g[h] * rsqrtf(var + 1e-5f);
    ca[h] = a;
    cb[h] = fmaf(-mu, a, be[h]);
}

// ---------------- pool: batch is sorted -> binary-search range per graph ----------------
__global__ __launch_bounds__(256) void k_pool(const float* __restrict__ z,
                                              const int* __restrict__ batch,
                                              float* __restrict__ out) {
    int g = blockIdx.x, h = threadIdx.x;
    int a = 0, b = NN;
    while (a < b) { int m = (a + b) >> 1; if (batch[m] < g) a = m + 1; else b = m; }
    int lo = a;
    b = NN;
    while (a < b) { int m = (a + b) >> 1; if (batch[m] < g + 1) a = m + 1; else b = m; }
    int hi = a;
    float s = 0.f;
    for (int n = lo; n < hi; ++n) s += z[(size_t)n * HH + h];
    out[(size_t)g * HH + h] = s;
}

extern "C" void kernel_launch(void* const* d_in, const int* in_sizes, int n_in,
                              void* d_out, int out_size, void* d_ws, size_t ws_size,
                              hipStream_t stream) {
    const int* x_feat = (const int*)d_in[0];
    const int* ei = (const int*)d_in[1];
    const int* attr = (const int*)d_in[2];
    const int* batch = (const int*)d_in[3];
    const float* atom_emb = (const float*)d_in[4];
    const float* bond_emb = (const float*)d_in[5];
    const float* W1 = (const float*)d_in[6];
    const float* b1 = (const float*)d_in[7];
    const float* g1 = (const float*)d_in[8];
    const float* be1 = (const float*)d_in[9];
    const float* W2 = (const float*)d_in[10];
    const float* b2 = (const float*)d_in[11];
    const float* g2 = (const float*)d_in[12];
    const float* be2 = (const float*)d_in[13];
    const float* outW1 = (const float*)d_in[14];
    const float* outb1 = (const float*)d_in[15];
    const float* outg = (const float*)d_in[16];
    const float* outbe = (const float*)d_in[17];
    const float* outW2 = (const float*)d_in[18];
    const float* outb2 = (const float*)d_in[19];
    float* out = (float*)d_out;

    char* ws = (char*)d_ws;
    const size_t NH_BYTES = (size_t)NN * HH * sizeof(float);
    float* bufA = (float*)ws;                       // t (pre-BN node features)
    float* bufB = (float*)(ws + NH_BYTES);          // agg
    float* bufC = (float*)(ws + 2 * NH_BYTES);      // y
    char* p = ws + 3 * NH_BYTES;
    int4* ebuf = (int4*)p;            p += (size_t)EE * sizeof(int4);
    int* deg = (int*)p;               p += (size_t)NN * sizeof(int);
    int* ro = (int*)p;                p += (size_t)(NN + 1) * sizeof(int);
    int* cursor = (int*)p;            p += (size_t)NN * sizeof(int);
    int* bsum = (int*)p;              p += 256 * sizeof(int);
    float* stats = (float*)p;         p += 11 * 512 * sizeof(float);  // [11][2][256]
    float* ca1 = (float*)p;           p += HH * sizeof(float);
    float* cb1 = (float*)p;           p += HH * sizeof(float);
    float* ca2 = (float*)p;           p += HH * sizeof(float);
    float* cb2 = (float*)p;           p += HH * sizeof(float);

    const float invN = 1.0f / (float)NN;
    const dim3 ggrid(782, 4);
    const int EBLK = (EE + 255) / 256;

    // --- CSR build (once; reused all layers) ---
    hipMemsetAsync(deg, 0, (size_t)NN * sizeof(int), stream);
    hipMemsetAsync(stats, 0, 11 * 512 * sizeof(float), stream);
    k_hist<<<EBLK, 256, 0, stream>>>(ei, deg);
    k_scan_a<<<NCHUNK, 256, 0, stream>>>(deg, ro, bsum);
    k_scan_b<<<1, 256, 0, stream>>>(bsum);
    k_scan_c<<<NCHUNK, 256, 0, stream>>>(ro, bsum, cursor);
    k_scatter<<<EBLK, 256, 0, stream>>>(ei, attr, cursor, ebuf);

    // --- encoder ---
    k_encode<<<NN, 256, 0, stream>>>(x_feat, atom_emb, bufA);

    const int AGG_GRID = (NN + 3) / 4;

    for (int l = 0; l < LL; ++l) {
        float* s1 = stats + (size_t)(2 * l) * 512;
        float* q1 = s1 + 256;
        float* s2 = stats + (size_t)(2 * l + 1) * 512;
        float* q2 = s2 + 256;
        const float* tca = (l == 0) ? nullptr : ca2;
        const float* tcb = (l == 0) ? nullptr : cb2;
        // agg = T(t) + sum relu(T(t[src]) + e)
        k_aggregate<<<AGG_GRID, 256, 0, stream>>>(bufA, ro, ebuf, bond_emb, tca, tcb, bufB);
        // y = agg @ W1 + b1   (+ stats for bn1)
        k_gemm<<<ggrid, 256, 0, stream>>>(bufB, W1 + (size_t)l * HH * HH, b1 + (size_t)l * HH,
                                          bufC, NN, 0, nullptr, nullptr, s1, q1);
        k_bncoeff<<<1, 256, 0, stream>>>(s1, q1, g1 + (size_t)l * HH, be1 + (size_t)l * HH,
                                         ca1, cb1, invN);
        // t' = relu(relu(bn1(y)) @ W2 + b2)   (+ stats for bn2)
        k_gemm<<<ggrid, 256, 0, stream>>>(bufC, W2 + (size_t)l * HH * HH, b2 + (size_t)l * HH,
                                          bufA, NN, 1, ca1, cb1, s2, q2);
        k_bncoeff<<<1, 256, 0, stream>>>(s2, q2, g2 + (size_t)l * HH, be2 + (size_t)l * HH,
                                         ca2, cb2, invN);
    }

    // --- head ---
    float* sH = stats + (size_t)10 * 512;
    float* qH = sH + 256;
    // y = T(t5) @ outW1 + outb1  (+ stats for out bn)
    k_gemm<<<ggrid, 256, 0, stream>>>(bufA, outW1, outb1, bufB, NN, 0, ca2, cb2, sH, qH);
    k_bncoeff<<<1, 256, 0, stream>>>(sH, qH, outg, outbe, ca1, cb1, invN);
    // z = relu(bnH(y)) @ outW2 + outb2
    k_gemm<<<ggrid, 256, 0, stream>>>(bufB, outW2, outb2, bufC, NN, 0, ca1, cb1, nullptr, nullptr);
    // pool
    k_pool<<<GG, 256, 0, stream>>>(bufC, batch, out);
}

// Round 3
// 1524.113 us; speedup vs baseline: 3.4960x; 1.7533x over previous
//
#include <hip/hip_runtime.h>
#include <hip/hip_bf16.h>
#include <string.h>

#define NN 50000
#define EE 800000
#define HH 256
#define GG 128
#define LL 5
#define NCHUNK 196  // ceil((NN+1)/256)

typedef __attribute__((ext_vector_type(8))) short short8_t;
typedef __attribute__((ext_vector_type(4))) float f32x4;
typedef __hip_bfloat16 bf16;

__device__ __forceinline__ float bf2f(unsigned short u) {
    unsigned int i = ((unsigned int)u) << 16;
    float f;
    __builtin_memcpy(&f, &i, 4);
    return f;
}
__device__ __forceinline__ unsigned short f2bf(float f) {
    bf16 h = __float2bfloat16(f);
    unsigned short u;
    __builtin_memcpy(&u, &h, 2);
    return u;
}

// ---------------- atom encoder: x[n,h] = sum_f atom_emb[f, feat[n,f], h] -> bf16 ----------------
__global__ __launch_bounds__(256) void k_encode(const int* __restrict__ xf,
                                                const float* __restrict__ atom_emb,
                                                bf16* __restrict__ x) {
    int n = blockIdx.x, h = threadIdx.x;
    float s = 0.f;
#pragma unroll
    for (int f = 0; f < 9; ++f) {
        int v = xf[n * 9 + f];
        s += atom_emb[((size_t)f * 64 + v) * HH + h];
    }
    x[(size_t)n * HH + h] = __float2bfloat16(s);
}

// ---------------- weight prep: Wt[z][n][k] = bf16(W[z][k][n]) ----------------
__global__ __launch_bounds__(256) void k_prepw(const float* __restrict__ W1,
                                               const float* __restrict__ W2,
                                               const float* __restrict__ oW1,
                                               const float* __restrict__ oW2,
                                               bf16* __restrict__ out) {
    int z = blockIdx.z;
    const float* src = (z < 5) ? W1 + (size_t)z * 65536
                     : (z < 10) ? W2 + (size_t)(z - 5) * 65536
                     : (z == 10) ? oW1 : oW2;
    bf16* dst = out + (size_t)z * 65536;
    __shared__ float tile[32][33];
    int kt = blockIdx.y * 32, nt = blockIdx.x * 32;
    int tx = threadIdx.x, ty = threadIdx.y;  // 32 x 8
    for (int i = ty; i < 32; i += 8) tile[i][tx] = src[(size_t)(kt + i) * 256 + nt + tx];
    __syncthreads();
    for (int i = ty; i < 32; i += 8)
        dst[(size_t)(nt + i) * 256 + kt + tx] = __float2bfloat16(tile[tx][i]);
}

// ---------------- CSR build ----------------
__global__ __launch_bounds__(256) void k_hist(const int* __restrict__ ei, int* __restrict__ deg) {
    int e = blockIdx.x * 256 + threadIdx.x;
    if (e < EE) atomicAdd(&deg[ei[EE + e]], 1);
}

__global__ __launch_bounds__(256) void k_scan_a(const int* __restrict__ deg, int* __restrict__ ro,
                                                int* __restrict__ bsum) {
    __shared__ int sm[256];
    int b = blockIdx.x, t = threadIdx.x;
    int idx = b * 256 + t;
    int v = (idx < NN) ? deg[idx] : 0;
    sm[t] = v;
    __syncthreads();
    for (int off = 1; off < 256; off <<= 1) {
        int add = (t >= off) ? sm[t - off] : 0;
        __syncthreads();
        sm[t] += add;
        __syncthreads();
    }
    if (idx <= NN) ro[idx] = sm[t] - v;
    if (t == 255) bsum[b] = sm[255];
}

__global__ __launch_bounds__(256) void k_scan_b(int* __restrict__ bsum) {
    __shared__ int sm[256];
    int t = threadIdx.x;
    int v = (t < NCHUNK) ? bsum[t] : 0;
    sm[t] = v;
    __syncthreads();
    for (int off = 1; off < 256; off <<= 1) {
        int add = (t >= off) ? sm[t - off] : 0;
        __syncthreads();
        sm[t] += add;
        __syncthreads();
    }
    if (t < NCHUNK) bsum[t] = sm[t] - v;
}

__global__ __launch_bounds__(256) void k_scan_c(int* __restrict__ ro, const int* __restrict__ bsum,
                                                int* __restrict__ cursor) {
    int b = blockIdx.x, t = threadIdx.x;
    int idx = b * 256 + t;
    if (idx <= NN) {
        int val = ro[idx] + bsum[b];
        ro[idx] = val;
        if (idx < NN) cursor[idx] = val;
    }
}

__global__ __launch_bounds__(256) void k_scatter(const int* __restrict__ ei,
                                                 const int* __restrict__ attr,
                                                 int* __restrict__ cursor,
                                                 int4* __restrict__ ebuf) {
    int e = blockIdx.x * 256 + threadIdx.x;
    if (e < EE) {
        int d = ei[EE + e];
        int pos = atomicAdd(&cursor[d], 1);
        ebuf[pos] = make_int4(ei[e], attr[e * 3], attr[e * 3 + 1], attr[e * 3 + 2]);
    }
}

// ---------------- fused aggregate (bf16 in/out) ----------------
// aggout[n] = T(t[n]) + sum_{e in in(n)} relu(T(t[src(e)]) + bond(e)), T = BN+relu fold
__global__ __launch_bounds__(256) void k_aggregate(const bf16* __restrict__ t,
                                                   const int* __restrict__ ro,
                                                   const int4* __restrict__ ebuf,
                                                   const float* __restrict__ bond_emb,
                                                   const float* __restrict__ ca,
                                                   const float* __restrict__ cb,
                                                   bf16* __restrict__ aggout) {
    int grp = threadIdx.x >> 6;
    int lane = threadIdx.x & 63;
    int n = blockIdx.x * 4 + grp;
    if (n >= NN) return;
    int h4 = lane * 4;
    bool has_t = (ca != nullptr);
    float4 cav = make_float4(1.f, 1.f, 1.f, 1.f);
    float4 cbv = make_float4(0.f, 0.f, 0.f, 0.f);
    if (has_t) {
        cav = *reinterpret_cast<const float4*>(&ca[h4]);
        cbv = *reinterpret_cast<const float4*>(&cb[h4]);
    }
    ushort4 tv = *reinterpret_cast<const ushort4*>(t + (size_t)n * HH + h4);
    float ax = bf2f(tv.x), ay = bf2f(tv.y), az = bf2f(tv.z), aw = bf2f(tv.w);
    if (has_t) {
        ax = fmaxf(fmaf(ax, cav.x, cbv.x), 0.f);
        ay = fmaxf(fmaf(ay, cav.y, cbv.y), 0.f);
        az = fmaxf(fmaf(az, cav.z, cbv.z), 0.f);
        aw = fmaxf(fmaf(aw, cav.w, cbv.w), 0.f);
    }
    int e0 = ro[n], e1 = ro[n + 1];
    for (int j = e0; j < e1; ++j) {
        int4 er = ebuf[j];
        const float4 b0 = *reinterpret_cast<const float4*>(&bond_emb[(size_t)(0 * 8 + er.y) * HH + h4]);
        const float4 b1 = *reinterpret_cast<const float4*>(&bond_emb[(size_t)(1 * 8 + er.z) * HH + h4]);
        const float4 b2 = *reinterpret_cast<const float4*>(&bond_emb[(size_t)(2 * 8 + er.w) * HH + h4]);
        ushort4 xs = *reinterpret_cast<const ushort4*>(t + (size_t)er.x * HH + h4);
        float vx = bf2f(xs.x), vy = bf2f(xs.y), vz = bf2f(xs.z), vw = bf2f(xs.w);
        if (has_t) {
            vx = fmaxf(fmaf(vx, cav.x, cbv.x), 0.f);
            vy = fmaxf(fmaf(vy, cav.y, cbv.y), 0.f);
            vz = fmaxf(fmaf(vz, cav.z, cbv.z), 0.f);
            vw = fmaxf(fmaf(vw, cav.w, cbv.w), 0.f);
        }
        ax += fmaxf(vx + b0.x + b1.x + b2.x, 0.f);
        ay += fmaxf(vy + b0.y + b1.y + b2.y, 0.f);
        az += fmaxf(vz + b0.z + b1.z + b2.z, 0.f);
        aw += fmaxf(vw + b0.w + b1.w + b2.w, 0.f);
    }
    ushort4 o;
    o.x = f2bf(ax); o.y = f2bf(ay); o.z = f2bf(az); o.w = f2bf(aw);
    *reinterpret_cast<ushort4*>(aggout + (size_t)n * HH + h4) = o;
}

// ---------------- MFMA GEMM: Out[M,256] = T(A)[M,256] @ W[256,256] + bias ----------------
// A bf16 row-major; Wt bf16 = W^T [N][K]. T folds BN+relu (per-k coeffs) at A staging.
// 128x128 tile, 4 waves (2x2 of 64x64), BK=32, mfma_f32_16x16x32_bf16.
__device__ __forceinline__ uint4 xform_chunk(uint4 u, const float* ca, const float* cb, int kbase) {
    float cav[8], cbv[8];
    *reinterpret_cast<float4*>(&cav[0]) = *reinterpret_cast<const float4*>(ca + kbase);
    *reinterpret_cast<float4*>(&cav[4]) = *reinterpret_cast<const float4*>(ca + kbase + 4);
    *reinterpret_cast<float4*>(&cbv[0]) = *reinterpret_cast<const float4*>(cb + kbase);
    *reinterpret_cast<float4*>(&cbv[4]) = *reinterpret_cast<const float4*>(cb + kbase + 4);
    unsigned int s[4] = {u.x, u.y, u.z, u.w};
#pragma unroll
    for (int p = 0; p < 4; ++p) {
        float lo = bf2f((unsigned short)(s[p] & 0xffffu));
        float hi = bf2f((unsigned short)(s[p] >> 16));
        lo = fmaxf(fmaf(lo, cav[2 * p], cbv[2 * p]), 0.f);
        hi = fmaxf(fmaf(hi, cav[2 * p + 1], cbv[2 * p + 1]), 0.f);
        s[p] = (unsigned int)f2bf(lo) | ((unsigned int)f2bf(hi) << 16);
    }
    return make_uint4(s[0], s[1], s[2], s[3]);
}

__global__ __launch_bounds__(256) void k_gemm(const bf16* __restrict__ A,
                                              const bf16* __restrict__ Wt,
                                              const float* __restrict__ bias,
                                              bf16* __restrict__ Out,
                                              int M, int do_relu,
                                              const float* __restrict__ tca,
                                              const float* __restrict__ tcb,
                                              float* __restrict__ ssum,
                                              float* __restrict__ ssq) {
    __shared__ uint4 lds4[1024];  // 16 KB: A-tile 8KB (chunks 0..511), B-tile 8KB (512..1023)
    char* ldsc = (char*)lds4;
    const int t = threadIdx.x;
    const int l = t & 63;
    const int w = t >> 6;
    const int wr = w >> 1, wc = w & 1;
    const int m0 = blockIdx.x * 128, n0 = blockIdx.y * 128;
    const int lhi = l >> 4;      // k-group 0..3
    const int llo = l & 15;      // row/col within 16

    const int ar = t & 127;      // staging row (A) / col (B)
    const int kg0 = t >> 7;      // 0 or 1; also stages kg0+2

    f32x4 acc[4][4] = {};

    const size_t arow = (size_t)(m0 + ar) * HH;
    const size_t brow = (size_t)(n0 + ar) * HH;

    for (int kb = 0; kb < 256; kb += 32) {
        uint4 a0 = *reinterpret_cast<const uint4*>(A + arow + kb + kg0 * 8);
        uint4 a1 = *reinterpret_cast<const uint4*>(A + arow + kb + (kg0 + 2) * 8);
        uint4 b0 = *reinterpret_cast<const uint4*>(Wt + brow + kb + kg0 * 8);
        uint4 b1 = *reinterpret_cast<const uint4*>(Wt + brow + kb + (kg0 + 2) * 8);
        if (tca) {
            a0 = xform_chunk(a0, tca, tcb, kb + kg0 * 8);
            a1 = xform_chunk(a1, tca, tcb, kb + (kg0 + 2) * 8);
        }
        __syncthreads();
        lds4[kg0 * 128 + ar] = a0;
        lds4[(kg0 + 2) * 128 + ar] = a1;
        lds4[512 + kg0 * 128 + ar] = b0;
        lds4[512 + (kg0 + 2) * 128 + ar] = b1;
        __syncthreads();
        short8_t af[4], bfr[4];
#pragma unroll
        for (int m = 0; m < 4; ++m)
            af[m] = *reinterpret_cast<const short8_t*>(ldsc + ((lhi * 128) + wr * 64 + m * 16 + llo) * 16);
#pragma unroll
        for (int n = 0; n < 4; ++n)
            bfr[n] = *reinterpret_cast<const short8_t*>(ldsc + 8192 + ((lhi * 128) + wc * 64 + n * 16 + llo) * 16);
#pragma unroll
        for (int m = 0; m < 4; ++m)
#pragma unroll
            for (int n = 0; n < 4; ++n)
                acc[m][n] = __builtin_amdgcn_mfma_f32_16x16x32_bf16(af[m], bfr[n], acc[m][n], 0, 0, 0);
    }

    // epilogue: bias (+relu), store bf16, optional column stats
    float bias_n[4];
    int col_n[4];
#pragma unroll
    for (int n = 0; n < 4; ++n) {
        col_n[n] = n0 + wc * 64 + n * 16 + llo;
        bias_n[n] = bias[col_n[n]];
    }
    float ps[4] = {0.f, 0.f, 0.f, 0.f}, pq[4] = {0.f, 0.f, 0.f, 0.f};
#pragma unroll
    for (int m = 0; m < 4; ++m) {
#pragma unroll
        for (int j = 0; j < 4; ++j) {
            int row = m0 + wr * 64 + m * 16 + lhi * 4 + j;
            bool valid = row < M;
#pragma unroll
            for (int n = 0; n < 4; ++n) {
                float v = acc[m][n][j] + bias_n[n];
                if (do_relu) v = fmaxf(v, 0.f);
                if (valid) {
                    Out[(size_t)row * HH + col_n[n]] = __float2bfloat16(v);
                    ps[n] += v;
                    pq[n] = fmaf(v, v, pq[n]);
                }
            }
        }
    }

    if (ssum) {
        __syncthreads();
        float* cs = (float*)ldsc;
        float* cq = cs + 128;
        if (t < 128) { cs[t] = 0.f; cq[t] = 0.f; }
        __syncthreads();
#pragma unroll
        for (int n = 0; n < 4; ++n) {
            float s = ps[n];
            s += __shfl_xor(s, 16);
            s += __shfl_xor(s, 32);
            float q = pq[n];
            q += __shfl_xor(q, 16);
            q += __shfl_xor(q, 32);
            if (lhi == 0) {
                atomicAdd(&cs[wc * 64 + n * 16 + llo], s);
                atomicAdd(&cq[wc * 64 + n * 16 + llo], q);
            }
        }
        __syncthreads();
        if (t < 128) {
            atomicAdd(&ssum[n0 + t], cs[t]);
            atomicAdd(&ssq[n0 + t], cq[t]);
        }
    }
}

__global__ void k_bncoeff(const float* __restrict__ ssum, const float* __restrict__ ssq,
                          const float* __restrict__ g, const float* __restrict__ be,
                          float* __restrict__ ca, float* __restrict__ cb, float invN) {
    int h = threadIdx.x;
    float mu = ssum[h] * invN;
    float var = ssq[h] * invN - mu * mu;
    float a = g[h] * rsqrtf(var + 1e-5f);
    ca[h] = a;
    cb[h] = fmaf(-mu, a, be[h]);
}

// ---------------- pool: batch sorted -> binary-search range per graph ----------------
__global__ __launch_bounds__(256) void k_pool(const bf16* __restrict__ z,
                                              const int* __restrict__ batch,
                                              float* __restrict__ out) {
    int g = blockIdx.x, h = threadIdx.x;
    int a = 0, b = NN;
    while (a < b) { int m = (a + b) >> 1; if (batch[m] < g) a = m + 1; else b = m; }
    int lo = a;
    b = NN;
    while (a < b) { int m = (a + b) >> 1; if (batch[m] < g + 1) a = m + 1; else b = m; }
    int hi = a;
    float s = 0.f;
    for (int n = lo; n < hi; ++n) s += bf2f(*(const unsigned short*)(z + (size_t)n * HH + h));
    out[(size_t)g * HH + h] = s;
}

extern "C" void kernel_launch(void* const* d_in, const int* in_sizes, int n_in,
                              void* d_out, int out_size, void* d_ws, size_t ws_size,
                              hipStream_t stream) {
    const int* x_feat = (const int*)d_in[0];
    const int* ei = (const int*)d_in[1];
    const int* attr = (const int*)d_in[2];
    const int* batch = (const int*)d_in[3];
    const float* atom_emb = (const float*)d_in[4];
    const float* bond_emb = (const float*)d_in[5];
    const float* W1 = (const float*)d_in[6];
    const float* b1 = (const float*)d_in[7];
    const float* g1 = (const float*)d_in[8];
    const float* be1 = (const float*)d_in[9];
    const float* W2 = (const float*)d_in[10];
    const float* b2 = (const float*)d_in[11];
    const float* g2 = (const float*)d_in[12];
    const float* be2 = (const float*)d_in[13];
    const float* outW1 = (const float*)d_in[14];
    const float* outb1 = (const float*)d_in[15];
    const float* outg = (const float*)d_in[16];
    const float* outbe = (const float*)d_in[17];
    const float* outW2 = (const float*)d_in[18];
    const float* outb2 = (const float*)d_in[19];
    float* out = (float*)d_out;

    char* ws = (char*)d_ws;
    // bf16 node buffers: NN*HH*2 bytes + 128 KB pad (GEMM tile OOB reads stay in-bounds)
    const size_t BUF_STRIDE = (size_t)NN * HH * 2 + 131072;
    bf16* bufA = (bf16*)ws;
    bf16* bufB = (bf16*)(ws + BUF_STRIDE);
    bf16* bufC = (bf16*)(ws + 2 * BUF_STRIDE);
    char* p = ws + 3 * BUF_STRIDE;
    int4* ebuf = (int4*)p;            p += (size_t)EE * sizeof(int4);
    int* deg = (int*)p;               p += (size_t)NN * sizeof(int);
    int* ro = (int*)p;                p += (size_t)(NN + 1) * sizeof(int);
    int* cursor = (int*)p;            p += (size_t)NN * sizeof(int);
    int* bsum = (int*)p;              p += 256 * sizeof(int);
    float* stats = (float*)p;         p += 11 * 512 * sizeof(float);  // [11][2][256]
    float* ca1 = (float*)p;           p += HH * sizeof(float);
    float* cb1 = (float*)p;           p += HH * sizeof(float);
    float* ca2 = (float*)p;           p += HH * sizeof(float);
    float* cb2 = (float*)p;           p += HH * sizeof(float);
    bf16* wbuf = (bf16*)p;            p += (size_t)12 * 65536 * sizeof(bf16);

    const float invN = 1.0f / (float)NN;
    const int EBLK = (EE + 255) / 256;
    const dim3 ggrid((NN + 127) / 128, 2);
    const int AGG_GRID = (NN + 3) / 4;

    // --- CSR build + weight prep + encoder ---
    hipMemsetAsync(deg, 0, (size_t)NN * sizeof(int), stream);
    hipMemsetAsync(stats, 0, 11 * 512 * sizeof(float), stream);
    k_hist<<<EBLK, 256, 0, stream>>>(ei, deg);
    k_scan_a<<<NCHUNK, 256, 0, stream>>>(deg, ro, bsum);
    k_scan_b<<<1, 256, 0, stream>>>(bsum);
    k_scan_c<<<NCHUNK, 256, 0, stream>>>(ro, bsum, cursor);
    k_scatter<<<EBLK, 256, 0, stream>>>(ei, attr, cursor, ebuf);
    k_prepw<<<dim3(8, 8, 12), dim3(32, 8), 0, stream>>>(W1, W2, outW1, outW2, wbuf);
    k_encode<<<NN, 256, 0, stream>>>(x_feat, atom_emb, bufA);

    for (int l = 0; l < LL; ++l) {
        float* s1 = stats + (size_t)(2 * l) * 512;
        float* q1 = s1 + 256;
        float* s2 = stats + (size_t)(2 * l + 1) * 512;
        float* q2 = s2 + 256;
        const float* tca = (l == 0) ? nullptr : ca2;
        const float* tcb = (l == 0) ? nullptr : cb2;
        // agg = T(t) + sum relu(T(t[src]) + e)
        k_aggregate<<<AGG_GRID, 256, 0, stream>>>(bufA, ro, ebuf, bond_emb, tca, tcb, bufB);
        // y = agg @ W1 + b1   (+ stats for bn1)
        k_gemm<<<ggrid, 256, 0, stream>>>(bufB, wbuf + (size_t)l * 65536, b1 + (size_t)l * HH,
                                          bufC, NN, 0, nullptr, nullptr, s1, q1);
        k_bncoeff<<<1, 256, 0, stream>>>(s1, q1, g1 + (size_t)l * HH, be1 + (size_t)l * HH,
                                         ca1, cb1, invN);
        // t' = relu(T1(y) @ W2 + b2)   (+ stats for bn2)
        k_gemm<<<ggrid, 256, 0, stream>>>(bufC, wbuf + (size_t)(5 + l) * 65536, b2 + (size_t)l * HH,
                                          bufA, NN, 1, ca1, cb1, s2, q2);
        k_bncoeff<<<1, 256, 0, stream>>>(s2, q2, g2 + (size_t)l * HH, be2 + (size_t)l * HH,
                                         ca2, cb2, invN);
    }

    // --- head ---
    float* sH = stats + (size_t)10 * 512;
    float* qH = sH + 256;
    k_gemm<<<ggrid, 256, 0, stream>>>(bufA, wbuf + (size_t)10 * 65536, outb1,
                                      bufB, NN, 0, ca2, cb2, sH, qH);
    k_bncoeff<<<1, 256, 0, stream>>>(sH, qH, outg, outbe, ca1, cb1, invN);
    k_gemm<<<ggrid, 256, 0, stream>>>(bufB, wbuf + (size_t)11 * 65536, outb2,
                                      bufC, NN, 0, ca1, cb1, nullptr, nullptr);
    k_pool<<<GG, 256, 0, stream>>>(bufC, batch, out);
}

// Round 4
// 1198.859 us; speedup vs baseline: 4.4444x; 1.2713x over previous
//
#include <hip/hip_runtime.h>
#include <hip/hip_bf16.h>

#define NN 50000
#define EE 800000
#define HH 256
#define GG 128
#define LL 5
#define NCHUNK 196  // ceil((NN+1)/256)
#define BN_EPS 1e-5f

typedef __attribute__((ext_vector_type(8))) short short8_t;
typedef __attribute__((ext_vector_type(4))) float f32x4;
typedef __hip_bfloat16 bf16;

__device__ __forceinline__ float bf2f(unsigned short u) {
    unsigned int i = ((unsigned int)u) << 16;
    float f;
    __builtin_memcpy(&f, &i, 4);
    return f;
}
__device__ __forceinline__ unsigned short f2bf(float f) {
    bf16 h = __float2bfloat16(f);
    unsigned short u;
    __builtin_memcpy(&u, &h, 2);
    return u;
}

// ---------------- atom encoder ----------------
__global__ __launch_bounds__(256) void k_encode(const int* __restrict__ xf,
                                                const float* __restrict__ atom_emb,
                                                bf16* __restrict__ x) {
    int n = blockIdx.x, h = threadIdx.x;
    float s = 0.f;
#pragma unroll
    for (int f = 0; f < 9; ++f) {
        int v = xf[n * 9 + f];
        s += atom_emb[((size_t)f * 64 + v) * HH + h];
    }
    x[(size_t)n * HH + h] = __float2bfloat16(s);
}

// ---------------- bond combo table: table[c][h] = sum of 3 bond embeddings ----------------
__global__ __launch_bounds__(256) void k_combo(const float* __restrict__ bond_emb,
                                               float* __restrict__ table) {
    int c = blockIdx.x, h = threadIdx.x;
    float v = bond_emb[(size_t)((c >> 6) & 7) * HH + h]
            + bond_emb[(size_t)(8 + ((c >> 3) & 7)) * HH + h]
            + bond_emb[(size_t)(16 + (c & 7)) * HH + h];
    table[(size_t)c * HH + h] = v;
}

// ---------------- weight prep: Wt[z][n][k] = bf16(W[z][k][n]) ----------------
__global__ __launch_bounds__(256) void k_prepw(const float* __restrict__ W1,
                                               const float* __restrict__ W2,
                                               const float* __restrict__ oW1,
                                               const float* __restrict__ oW2,
                                               bf16* __restrict__ out) {
    int z = blockIdx.z;
    const float* src = (z < 5) ? W1 + (size_t)z * 65536
                     : (z < 10) ? W2 + (size_t)(z - 5) * 65536
                     : (z == 10) ? oW1 : oW2;
    bf16* dst = out + (size_t)z * 65536;
    __shared__ float tile[32][33];
    int kt = blockIdx.y * 32, nt = blockIdx.x * 32;
    int tx = threadIdx.x, ty = threadIdx.y;  // 32 x 8
    for (int i = ty; i < 32; i += 8) tile[i][tx] = src[(size_t)(kt + i) * 256 + nt + tx];
    __syncthreads();
    for (int i = ty; i < 32; i += 8)
        dst[(size_t)(nt + i) * 256 + kt + tx] = __float2bfloat16(tile[tx][i]);
}

// ---------------- CSR build ----------------
__global__ __launch_bounds__(256) void k_hist(const int* __restrict__ ei, int* __restrict__ deg) {
    int e = blockIdx.x * 256 + threadIdx.x;
    if (e < EE) atomicAdd(&deg[ei[EE + e]], 1);
}

__global__ __launch_bounds__(256) void k_scan_a(const int* __restrict__ deg, int* __restrict__ ro,
                                                int* __restrict__ bsum) {
    __shared__ int sm[256];
    int b = blockIdx.x, t = threadIdx.x;
    int idx = b * 256 + t;
    int v = (idx < NN) ? deg[idx] : 0;
    sm[t] = v;
    __syncthreads();
    for (int off = 1; off < 256; off <<= 1) {
        int add = (t >= off) ? sm[t - off] : 0;
        __syncthreads();
        sm[t] += add;
        __syncthreads();
    }
    if (idx <= NN) ro[idx] = sm[t] - v;
    if (t == 255) bsum[b] = sm[255];
}

__global__ __launch_bounds__(256) void k_scan_b(int* __restrict__ bsum) {
    __shared__ int sm[256];
    int t = threadIdx.x;
    int v = (t < NCHUNK) ? bsum[t] : 0;
    sm[t] = v;
    __syncthreads();
    for (int off = 1; off < 256; off <<= 1) {
        int add = (t >= off) ? sm[t - off] : 0;
        __syncthreads();
        sm[t] += add;
        __syncthreads();
    }
    if (t < NCHUNK) bsum[t] = sm[t] - v;
}

__global__ __launch_bounds__(256) void k_scan_c(int* __restrict__ ro, const int* __restrict__ bsum,
                                                int* __restrict__ cursor) {
    int b = blockIdx.x, t = threadIdx.x;
    int idx = b * 256 + t;
    if (idx <= NN) {
        int val = ro[idx] + bsum[b];
        ro[idx] = val;
        if (idx < NN) cursor[idx] = val;
    }
}

__global__ __launch_bounds__(256) void k_scatter(const int* __restrict__ ei,
                                                 const int* __restrict__ attr,
                                                 int* __restrict__ cursor,
                                                 int2* __restrict__ ebuf) {
    int e = blockIdx.x * 256 + threadIdx.x;
    if (e < EE) {
        int d = ei[EE + e];
        int c = (attr[e * 3] << 6) | (attr[e * 3 + 1] << 3) | attr[e * 3 + 2];
        int pos = atomicAdd(&cursor[d], 1);
        ebuf[pos] = make_int2(ei[e], c);
    }
}

// ---------------- fused aggregate ----------------
// agg[n] = T(t[n]) + sum_e relu(T(t[src]) + combo[c]);  T = BN(stats)+relu (HAS_T) or identity
template <bool HAS_T>
__global__ __launch_bounds__(256) void k_aggregate(const bf16* __restrict__ t,
                                                   const int* __restrict__ ro,
                                                   const int2* __restrict__ eb,
                                                   const float* __restrict__ combo,
                                                   const float* __restrict__ sIn,
                                                   const float* __restrict__ qIn,
                                                   const float* __restrict__ gIn,
                                                   const float* __restrict__ beIn,
                                                   float invN,
                                                   bf16* __restrict__ aggout) {
    int grp = threadIdx.x >> 6;
    int lane = threadIdx.x & 63;
    int n = blockIdx.x * 4 + grp;
    if (n >= NN) return;
    int h4 = lane * 4;
    float4 cav, cbv;
    if (HAS_T) {
        float4 s4 = *(const float4*)(sIn + h4);
        float4 q4 = *(const float4*)(qIn + h4);
        float4 g4 = *(const float4*)(gIn + h4);
        float4 b4 = *(const float4*)(beIn + h4);
#define COEF(C)                                                     \
        { float mu = s4.C * invN;                                   \
          float var = fmaf(-mu, mu, q4.C * invN);                   \
          float a = g4.C * rsqrtf(var + BN_EPS);                    \
          cav.C = a; cbv.C = fmaf(-mu, a, b4.C); }
        COEF(x) COEF(y) COEF(z) COEF(w)
#undef COEF
    }
#define TX(v, C) (HAS_T ? fmaxf(fmaf((v), cav.C, cbv.C), 0.f) : (v))
    ushort4 tv = *(const ushort4*)(t + (size_t)n * HH + h4);
    float4 acc, acc2 = make_float4(0.f, 0.f, 0.f, 0.f);
    acc.x = TX(bf2f(tv.x), x);
    acc.y = TX(bf2f(tv.y), y);
    acc.z = TX(bf2f(tv.z), z);
    acc.w = TX(bf2f(tv.w), w);
    int j = ro[n], e1 = ro[n + 1];
    for (; j + 2 <= e1; j += 2) {
        int2 r0 = eb[j];
        int2 r1 = eb[j + 1];
        ushort4 x0 = *(const ushort4*)(t + (size_t)r0.x * HH + h4);
        float4 c0 = *(const float4*)(combo + (size_t)r0.y * HH + h4);
        ushort4 x1 = *(const ushort4*)(t + (size_t)r1.x * HH + h4);
        float4 c1 = *(const float4*)(combo + (size_t)r1.y * HH + h4);
        acc.x += fmaxf(TX(bf2f(x0.x), x) + c0.x, 0.f);
        acc.y += fmaxf(TX(bf2f(x0.y), y) + c0.y, 0.f);
        acc.z += fmaxf(TX(bf2f(x0.z), z) + c0.z, 0.f);
        acc.w += fmaxf(TX(bf2f(x0.w), w) + c0.w, 0.f);
        acc2.x += fmaxf(TX(bf2f(x1.x), x) + c1.x, 0.f);
        acc2.y += fmaxf(TX(bf2f(x1.y), y) + c1.y, 0.f);
        acc2.z += fmaxf(TX(bf2f(x1.z), z) + c1.z, 0.f);
        acc2.w += fmaxf(TX(bf2f(x1.w), w) + c1.w, 0.f);
    }
    if (j < e1) {
        int2 r0 = eb[j];
        ushort4 x0 = *(const ushort4*)(t + (size_t)r0.x * HH + h4);
        float4 c0 = *(const float4*)(combo + (size_t)r0.y * HH + h4);
        acc.x += fmaxf(TX(bf2f(x0.x), x) + c0.x, 0.f);
        acc.y += fmaxf(TX(bf2f(x0.y), y) + c0.y, 0.f);
        acc.z += fmaxf(TX(bf2f(x0.z), z) + c0.z, 0.f);
        acc.w += fmaxf(TX(bf2f(x0.w), w) + c0.w, 0.f);
    }
#undef TX
    ushort4 o;
    o.x = f2bf(acc.x + acc2.x);
    o.y = f2bf(acc.y + acc2.y);
    o.z = f2bf(acc.z + acc2.z);
    o.w = f2bf(acc.w + acc2.w);
    *(ushort4*)(aggout + (size_t)n * HH + h4) = o;
}

// ---------------- MFMA GEMM v2: Out[M,256] = T(A) @ W + bias ----------------
// double-buffered, 1 barrier per K-step; B via global_load_lds; A reg-staged
// (issue-early / write-late) with optional BN+relu transform (coeffs from raw stats).
struct GLds {
    uint4 a[2][512];   // 2 x 8 KB: chunk idx = kg*128 + row (kg=0..3 of 8 bf16)
    uint4 b[2][512];   // 2 x 8 KB
    float ca[256], cb[256];
};

__device__ __forceinline__ uint4 xchunk(uint4 u, const float* ca, const float* cb, int k0) {
    float4 ca0 = *(const float4*)(ca + k0);
    float4 ca1 = *(const float4*)(ca + k0 + 4);
    float4 cb0 = *(const float4*)(cb + k0);
    float4 cb1 = *(const float4*)(cb + k0 + 4);
    float cav[8] = {ca0.x, ca0.y, ca0.z, ca0.w, ca1.x, ca1.y, ca1.z, ca1.w};
    float cbv[8] = {cb0.x, cb0.y, cb0.z, cb0.w, cb1.x, cb1.y, cb1.z, cb1.w};
    unsigned int s[4] = {u.x, u.y, u.z, u.w};
#pragma unroll
    for (int p = 0; p < 4; ++p) {
        float lo = bf2f((unsigned short)(s[p] & 0xffffu));
        float hi = bf2f((unsigned short)(s[p] >> 16));
        lo = fmaxf(fmaf(lo, cav[2 * p], cbv[2 * p]), 0.f);
        hi = fmaxf(fmaf(hi, cav[2 * p + 1], cbv[2 * p + 1]), 0.f);
        s[p] = (unsigned int)f2bf(lo) | ((unsigned int)f2bf(hi) << 16);
    }
    return make_uint4(s[0], s[1], s[2], s[3]);
}

__global__ __launch_bounds__(256) void k_gemm(const bf16* __restrict__ A,
                                              const bf16* __restrict__ Wt,
                                              const float* __restrict__ bias,
                                              bf16* __restrict__ Out,
                                              int M, int do_relu,
                                              const float* __restrict__ sIn,
                                              const float* __restrict__ qIn,
                                              const float* __restrict__ gIn,
                                              const float* __restrict__ beIn,
                                              float invN,
                                              float* __restrict__ ssum,
                                              float* __restrict__ ssq) {
    __shared__ GLds L;
    const int t = threadIdx.x;
    const int l = t & 63;
    const int w = t >> 6;
    const int wr = w >> 1, wc = w & 1;
    const int m0 = blockIdx.x * 128, n0 = blockIdx.y * 128;
    const int lhi = l >> 4, llo = l & 15;
    const int ar = t & 127, kgp = t >> 7;
    const bool tca = (sIn != nullptr);

    if (tca) {
        float mu = sIn[t] * invN;
        float var = fmaf(-mu, mu, qIn[t] * invN);
        float a = gIn[t] * rsqrtf(var + BN_EPS);
        L.ca[t] = a;
        L.cb[t] = fmaf(-mu, a, beIn[t]);
        __syncthreads();
    }

    const size_t arow = (size_t)(m0 + ar) * HH;
    const size_t brow = (size_t)(n0 + ar) * HH;
    const int bbase = (w >> 1) * 128 + (w & 1) * 64;  // wave-uniform dst chunk base

    f32x4 acc[4][4] = {};

#define STAGE_B(c, kb)                                                                        \
    {                                                                                         \
        const bf16* s1 = Wt + brow + (kb) + (w >> 1) * 8;                                     \
        __builtin_amdgcn_global_load_lds((const __attribute__((address_space(1))) void*)s1,   \
            (__attribute__((address_space(3))) void*)&L.b[c][bbase], 16, 0, 0);               \
        __builtin_amdgcn_global_load_lds(                                                     \
            (const __attribute__((address_space(1))) void*)(s1 + 16),                         \
            (__attribute__((address_space(3))) void*)&L.b[c][bbase + 256], 16, 0, 0);         \
    }
#define LOAD_A(kb, a0, a1)                                                                    \
    {                                                                                         \
        a0 = *(const uint4*)(A + arow + (kb) + kgp * 8);                                      \
        a1 = *(const uint4*)(A + arow + (kb) + (kgp + 2) * 8);                                \
    }
#define WRITE_A(c, kb, a0, a1)                                                                \
    {                                                                                         \
        uint4 w0 = a0, w1 = a1;                                                               \
        if (tca) {                                                                            \
            w0 = xchunk(w0, L.ca, L.cb, (kb) + kgp * 8);                                      \
            w1 = xchunk(w1, L.ca, L.cb, (kb) + (kgp + 2) * 8);                                \
        }                                                                                     \
        L.a[c][kgp * 128 + ar] = w0;                                                          \
        L.a[c][(kgp + 2) * 128 + ar] = w1;                                                    \
    }

    {
        uint4 a0, a1;
        STAGE_B(0, 0);
        LOAD_A(0, a0, a1);
        WRITE_A(0, 0, a0, a1);
    }
    __syncthreads();
    int c = 0;
    for (int step = 0; step < 8; ++step) {
        uint4 na0, na1;
        const int kn = (step + 1) * 32;
        if (step < 7) {
            STAGE_B(c ^ 1, kn);
            LOAD_A(kn, na0, na1);
        }
        short8_t af[4], bfv[4];
#pragma unroll
        for (int m = 0; m < 4; ++m)
            af[m] = *(const short8_t*)&L.a[c][lhi * 128 + wr * 64 + m * 16 + llo];
#pragma unroll
        for (int n = 0; n < 4; ++n)
            bfv[n] = *(const short8_t*)&L.b[c][lhi * 128 + wc * 64 + n * 16 + llo];
#pragma unroll
        for (int m = 0; m < 4; ++m)
#pragma unroll
            for (int n = 0; n < 4; ++n)
                acc[m][n] = __builtin_amdgcn_mfma_f32_16x16x32_bf16(af[m], bfv[n], acc[m][n], 0, 0, 0);
        if (step < 7) WRITE_A(c ^ 1, kn, na0, na1);
        __syncthreads();
        c ^= 1;
    }
#undef STAGE_B
#undef LOAD_A
#undef WRITE_A

    // epilogue: bias (+relu), store bf16, optional column stats
    float bias_n[4];
    int col_n[4];
#pragma unroll
    for (int n = 0; n < 4; ++n) {
        col_n[n] = n0 + wc * 64 + n * 16 + llo;
        bias_n[n] = bias[col_n[n]];
    }
    float ps[4] = {0.f, 0.f, 0.f, 0.f}, pq[4] = {0.f, 0.f, 0.f, 0.f};
#pragma unroll
    for (int m = 0; m < 4; ++m) {
#pragma unroll
        for (int j = 0; j < 4; ++j) {
            int row = m0 + wr * 64 + m * 16 + lhi * 4 + j;
            bool valid = row < M;
#pragma unroll
            for (int n = 0; n < 4; ++n) {
                float v = acc[m][n][j] + bias_n[n];
                if (do_relu) v = fmaxf(v, 0.f);
                if (valid) {
                    Out[(size_t)row * HH + col_n[n]] = __float2bfloat16(v);
                    ps[n] += v;
                    pq[n] = fmaf(v, v, pq[n]);
                }
            }
        }
    }

    if (ssum) {
        __syncthreads();
        float* cs = (float*)&L;
        float* cq = cs + 128;
        if (t < 128) { cs[t] = 0.f; cq[t] = 0.f; }
        __syncthreads();
#pragma unroll
        for (int n = 0; n < 4; ++n) {
            float s = ps[n];
            s += __shfl_xor(s, 16);
            s += __shfl_xor(s, 32);
            float q = pq[n];
            q += __shfl_xor(q, 16);
            q += __shfl_xor(q, 32);
            if (lhi == 0) {
                atomicAdd(&cs[wc * 64 + n * 16 + llo], s);
                atomicAdd(&cq[wc * 64 + n * 16 + llo], q);
            }
        }
        __syncthreads();
        if (t < 128) {
            atomicAdd(&ssum[n0 + t], cs[t]);
            atomicAdd(&ssq[n0 + t], cq[t]);
        }
    }
}

// ---------------- pool: batch sorted -> binary-search range per graph ----------------
__global__ __launch_bounds__(64) void k_pool(const bf16* __restrict__ z,
                                             const int* __restrict__ batch,
                                             float* __restrict__ out) {
    int g = blockIdx.x;
    int h = blockIdx.y * 64 + threadIdx.x;
    int a = 0, b = NN;
    while (a < b) { int m = (a + b) >> 1; if (batch[m] < g) a = m + 1; else b = m; }
    int lo = a;
    b = NN;
    while (a < b) { int m = (a + b) >> 1; if (batch[m] < g + 1) a = m + 1; else b = m; }
    int hi = a;
    float s = 0.f;
    for (int n = lo; n < hi; ++n) s += bf2f(*(const unsigned short*)(z + (size_t)n * HH + h));
    out[(size_t)g * HH + h] = s;
}

extern "C" void kernel_launch(void* const* d_in, const int* in_sizes, int n_in,
                              void* d_out, int out_size, void* d_ws, size_t ws_size,
                              hipStream_t stream) {
    const int* x_feat = (const int*)d_in[0];
    const int* ei = (const int*)d_in[1];
    const int* attr = (const int*)d_in[2];
    const int* batch = (const int*)d_in[3];
    const float* atom_emb = (const float*)d_in[4];
    const float* bond_emb = (const float*)d_in[5];
    const float* W1 = (const float*)d_in[6];
    const float* b1 = (const float*)d_in[7];
    const float* g1 = (const float*)d_in[8];
    const float* be1 = (const float*)d_in[9];
    const float* W2 = (const float*)d_in[10];
    const float* b2 = (const float*)d_in[11];
    const float* g2 = (const float*)d_in[12];
    const float* be2 = (const float*)d_in[13];
    const float* outW1 = (const float*)d_in[14];
    const float* outb1 = (const float*)d_in[15];
    const float* outg = (const float*)d_in[16];
    const float* outbe = (const float*)d_in[17];
    const float* outW2 = (const float*)d_in[18];
    const float* outb2 = (const float*)d_in[19];
    float* out = (float*)d_out;

    char* ws = (char*)d_ws;
    const size_t BUF_STRIDE = (size_t)NN * HH * 2 + 131072;  // bf16 + GEMM OOB pad
    bf16* bufA = (bf16*)ws;                       // t / node features
    bf16* bufB = (bf16*)(ws + BUF_STRIDE);        // agg
    bf16* bufC = (bf16*)(ws + 2 * BUF_STRIDE);    // y
    char* p = ws + 3 * BUF_STRIDE;
    int2* ebuf = (int2*)p;            p += (size_t)EE * sizeof(int2);
    int* deg = (int*)p;               p += (size_t)NN * sizeof(int);
    int* ro = (int*)p;                p += (size_t)(NN + 1) * sizeof(int);
    int* cursor = (int*)p;            p += (size_t)NN * sizeof(int);
    int* bsum = (int*)p;              p += 256 * sizeof(int);
    float* stats = (float*)p;         p += 11 * 512 * sizeof(float);  // [11][2][256]
    float* combo = (float*)p;         p += (size_t)512 * HH * sizeof(float);
    bf16* wbuf = (bf16*)p;            p += (size_t)12 * 65536 * sizeof(bf16);

    const float invN = 1.0f / (float)NN;
    const int EBLK = (EE + 255) / 256;
    const dim3 ggrid((NN + 127) / 128, 2);
    const int AGG_GRID = (NN + 3) / 4;

    // --- one-time prep ---
    hipMemsetAsync(deg, 0, (size_t)NN * sizeof(int), stream);
    hipMemsetAsync(stats, 0, 11 * 512 * sizeof(float), stream);
    k_hist<<<EBLK, 256, 0, stream>>>(ei, deg);
    k_scan_a<<<NCHUNK, 256, 0, stream>>>(deg, ro, bsum);
    k_scan_b<<<1, 256, 0, stream>>>(bsum);
    k_scan_c<<<NCHUNK, 256, 0, stream>>>(ro, bsum, cursor);
    k_scatter<<<EBLK, 256, 0, stream>>>(ei, attr, cursor, ebuf);
    k_combo<<<512, 256, 0, stream>>>(bond_emb, combo);
    k_prepw<<<dim3(8, 8, 12), dim3(32, 8), 0, stream>>>(W1, W2, outW1, outW2, wbuf);
    k_encode<<<NN, 256, 0, stream>>>(x_feat, atom_emb, bufA);

    for (int l = 0; l < LL; ++l) {
        float* s1 = stats + (size_t)(2 * l) * 512;
        float* q1 = s1 + 256;
        float* s2 = stats + (size_t)(2 * l + 1) * 512;
        float* q2 = s2 + 256;
        // agg = T(t) + sum relu(T(t[src]) + combo)   (T from prev layer's bn2 stats)
        if (l == 0) {
            k_aggregate<false><<<AGG_GRID, 256, 0, stream>>>(
                bufA, ro, ebuf, combo, nullptr, nullptr, nullptr, nullptr, invN, bufB);
        } else {
            float* sp = stats + (size_t)(2 * l - 1) * 512;
            k_aggregate<true><<<AGG_GRID, 256, 0, stream>>>(
                bufA, ro, ebuf, combo, sp, sp + 256,
                g2 + (size_t)(l - 1) * HH, be2 + (size_t)(l - 1) * HH, invN, bufB);
        }
        // y = agg @ W1 + b1   (+ stats for bn1)
        k_gemm<<<ggrid, 256, 0, stream>>>(bufB, wbuf + (size_t)l * 65536, b1 + (size_t)l * HH,
                                          bufC, NN, 0, nullptr, nullptr, nullptr, nullptr,
                                          invN, s1, q1);
        // t' = relu(T1(y) @ W2 + b2)   (+ stats for bn2)
        k_gemm<<<ggrid, 256, 0, stream>>>(bufC, wbuf + (size_t)(5 + l) * 65536, b2 + (size_t)l * HH,
                                          bufA, NN, 1, s1, q1,
                                          g1 + (size_t)l * HH, be1 + (size_t)l * HH,
                                          invN, s2, q2);
    }

    // --- head ---
    float* sP = stats + (size_t)9 * 512;   // layer-4 bn2 stats
    float* sH = stats + (size_t)10 * 512;
    float* qH = sH + 256;
    k_gemm<<<ggrid, 256, 0, stream>>>(bufA, wbuf + (size_t)10 * 65536, outb1,
                                      bufB, NN, 0, sP, sP + 256,
                                      g2 + (size_t)4 * HH, be2 + (size_t)4 * HH,
                                      invN, sH, qH);
    k_gemm<<<ggrid, 256, 0, stream>>>(bufB, wbuf + (size_t)11 * 65536, outb2,
                                      bufC, NN, 0, sH, qH, outg, outbe,
                                      invN, nullptr, nullptr);
    k_pool<<<dim3(GG, 4), 64, 0, stream>>>(bufC, batch, out);
}